// Round 4
// baseline (95345.172 us; speedup 1.0000x reference)
//
#include <hip/hip_runtime.h>

#define Bn 64
#define Nn 1024
#define Mn 1024
#define GSTR 7680
// scale = 2*log2(e): exp2(scale*x) = exp(2x)
#define KSCALE 2.8853900817779268f

typedef unsigned short u16;
typedef _Float16 h2 __attribute__((ext_vector_type(2)));

__device__ __forceinline__ float us2f(u16 u) {
    _Float16 h = __builtin_bit_cast(_Float16, u);
    return (float)h;
}
__device__ __forceinline__ u16 f2h(float f) {
    _Float16 h = (_Float16)f;
    return __builtin_bit_cast(u16, h);
}
__device__ __forceinline__ float rcp_fast(float x) {
#if __has_builtin(__builtin_amdgcn_rcpf)
    return __builtin_amdgcn_rcpf(x);
#else
    return 1.0f / x;
#endif
}
__device__ __forceinline__ float exp2_fast(float x) {
#if __has_builtin(__builtin_amdgcn_exp2f)
    return __builtin_amdgcn_exp2f(x);
#else
    return exp2f(x);
#endif
}
__device__ __forceinline__ float wsum(float x) {
#pragma unroll
    for (int m = 32; m > 0; m >>= 1) x += __shfl_xor(x, m, 64);
    return x;
}
__device__ __forceinline__ float wmax(float x) {
#pragma unroll
    for (int m = 32; m > 0; m >>= 1) x = fmaxf(x, __shfl_xor(x, m, 64));
    return x;
}
__device__ __forceinline__ float dot2(h2 a, h2 b, float c) {
#if __has_builtin(__builtin_amdgcn_fdot2)
    return __builtin_amdgcn_fdot2(a, b, c, false);
#else
    return c + (float)a.x * (float)b.x + (float)a.y * (float)b.y;
#endif
}

// ---------- precompute: 32-row tile of  out = scale * U @ W^T  (f16 out) ----------
__global__ __launch_bounds__(256)
void gemm_f16(const float* __restrict__ U, const float* __restrict__ W,
              u16* __restrict__ outN, u16* __restrict__ outT,
              int transposed, float scale) {
    __shared__ float WL[256 * 33];
    __shared__ float uL[32 * 33];
    const int tid = threadIdx.x;
    const size_t row0 = (size_t)blockIdx.x * 32;
    float acc[32];
#pragma unroll
    for (int m = 0; m < 32; ++m) acc[m] = 0.f;
    for (int ic = 0; ic < 8; ++ic) {
        __syncthreads();
        for (int e = tid; e < 8192; e += 256) {
            int h = e >> 5, ii = e & 31;
            WL[h * 33 + ii] = W[h * 256 + ic * 32 + ii];
        }
        for (int e = tid; e < 1024; e += 256) {
            int r = e >> 5, ii = e & 31;
            uL[r * 33 + ii] = U[(row0 + r) * 256 + ic * 32 + ii];
        }
        __syncthreads();
#pragma unroll 4
        for (int ii = 0; ii < 32; ++ii) {
            float w = WL[tid * 33 + ii];
#pragma unroll
            for (int m = 0; m < 32; ++m)
                acc[m] = fmaf(w, uL[m * 33 + ii], acc[m]);
        }
    }
    if (!transposed) {
#pragma unroll
        for (int m = 0; m < 32; ++m)
            outN[(row0 + m) * 256 + tid] = f2h(scale * acc[m]);
    } else {
        __syncthreads();
#pragma unroll
        for (int m = 0; m < 32; ++m) WL[tid * 33 + m] = acc[m];
        __syncthreads();
        const size_t batch = row0 >> 10;
        const int m0 = (int)(row0 & 1023);
        for (int e = tid; e < 8192; e += 256) {
            int h = e >> 5, mm = e & 31;
            outT[(batch * 256 + h) * 1024 + m0 + mm] = f2h(scale * WL[h * 33 + mm]);
        }
    }
}

__global__ void cast_f16s(const float* __restrict__ src, u16* __restrict__ dst,
                          int n, float scale) {
    int i = blockIdx.x * blockDim.x + threadIdx.x;
    if (i < n) dst[i] = f2h(scale * src[i]);
}

// uq [64][1024 m][256 i] f32  ->  [64][256 i][1024 m] f16
__global__ __launch_bounds__(256)
void uq_f16T(const float* __restrict__ uq, u16* __restrict__ out) {
    __shared__ float T[32][33];
    const int blk = blockIdx.x;
    const int it = blk & 7, mt = (blk >> 3) & 31, b = blk >> 8;
    const int tx = threadIdx.x & 31, ty = threadIdx.x >> 5;   // ty 0..7
#pragma unroll
    for (int k = 0; k < 4; ++k) {
        int mr = ty + 8 * k;
        T[mr][tx] = uq[((size_t)b * 1024 + mt * 32 + mr) * 256 + it * 32 + tx];
    }
    __syncthreads();
#pragma unroll
    for (int k = 0; k < 4; ++k) {
        int ir = ty + 8 * k;
        out[((size_t)b * 256 + it * 32 + ir) * 1024 + mt * 32 + tx] = f2h(T[tx][ir]);
    }
}

// -------- 4-block group barrier (device-scope), unchanged from passing version --------
__device__ __forceinline__ void group_barrier(unsigned int* ctr, unsigned int target,
                                              long long& budget) {
    __syncthreads();
    if (threadIdx.x == 0) {
        __threadfence();
        __hip_atomic_fetch_add(ctr, 1u, __ATOMIC_RELEASE, __HIP_MEMORY_SCOPE_AGENT);
        while (__hip_atomic_load(ctr, __ATOMIC_ACQUIRE, __HIP_MEMORY_SCOPE_AGENT) < target) {
            __builtin_amdgcn_s_sleep(1);
            if (--budget < 0) break;   // fail fast instead of deadlocking
        }
        __threadfence();
    }
    __syncthreads();
}

__global__ __launch_bounds__(1024, 4)
void scan_kernel(const float* __restrict__ up, const float* __restrict__ v0,
                 const float* __restrict__ V, const float* __restrict__ b_ih,
                 const float* __restrict__ b_hh,
                 const u16* __restrict__ WuqT, const u16* __restrict__ Pm,
                 const u16* __restrict__ uqT, const u16* __restrict__ Wv16,
                 const u16* __restrict__ wih16, const u16* __restrict__ whh16,
                 const u16* __restrict__ Wg216,
                 float* __restrict__ out, unsigned int* __restrict__ ctrs,
                 float* __restrict__ gdata) {
    const int tid = threadIdx.x;
    const int bid = blockIdx.x;
    // co-locate a batch's 4 blocks on one XCD (bid%8 = XCD under round-robin dispatch)
    const int x = bid & 7, q = (bid >> 3) & 3, bhi = bid >> 5;
    const int b = (bhi << 3) | x;

    unsigned int* ctr = ctrs + b * 16;
    float* gb = gdata + (size_t)b * GSTR;
    float* cpartB = gb;          // [4][256]
    float* mlsB   = gb + 1024;   // [8]
    float* giPB   = gb + 1032;   // [4][768]
    float* ghPB   = gb + 4104;   // [4][768]

    __shared__ __align__(16) u16 WuqL[256 * 256];    // [h][m-slice] f16, 128 KB
    __shared__ __align__(16) float scratch[8 * 256];
    __shared__ __align__(16) float2 dvLds[256];      // .x = d (K-scaled), .y = 2*V
    __shared__ float vLds[256], eLds[256], pnLds[256], rLds[512];
    __shared__ u16 vHu[256], rH[512], cLdsH[64];
    __shared__ float bihs[768], bhhs[768];
    __shared__ float red[32];
    __shared__ float svv_sh;

    // ---- one-time: stage this block's Wuq m-slice into LDS ----
    {
        const u16* src = WuqT + (size_t)b * 256 * 1024 + q * 256;
        for (int d = tid; d < 32768; d += 1024) {          // dwords
            int h = d >> 7, mp = d & 127;
            ((unsigned*)WuqL)[d] = *(const unsigned*)(src + (size_t)h * 1024 + mp * 2);
        }
    }
    if (tid < 768) { bihs[tid] = b_ih[tid]; bhhs[tid] = b_hh[tid]; }
    float vvreg = 0.f;
    if (tid < 256) {
        float v = v0[b * 256 + tid];
        vLds[tid] = v;
        vHu[tid] = f2h(v);
        vvreg = 2.0f * V[b * 256 + tid];
        pnLds[tid] = us2f(Pm[(size_t)b * Nn * 256 + tid]);
    }
    __syncthreads();
    if (tid < 256) {
        float s = wsum(vvreg);
        if ((tid & 63) == 0) red[tid >> 6] = s;
    }
    // initial d = pn + Wv@v0 (K-scaled), thread-private over j-chunk
    {
        const int h = tid & 255, jc = tid >> 8;
        const uint4* wr = (const uint4*)(Wv16 + (size_t)h * 256 + jc * 64);
        const h2* v2 = (const h2*)vHu;
        float acc = 0.f;
#pragma unroll
        for (int c8 = 0; c8 < 8; ++c8) {
            uint4 Wd = wr[c8];
            int kb = jc * 32 + c8 * 4;
            acc = dot2(__builtin_bit_cast(h2, Wd.x), v2[kb + 0], acc);
            acc = dot2(__builtin_bit_cast(h2, Wd.y), v2[kb + 1], acc);
            acc = dot2(__builtin_bit_cast(h2, Wd.z), v2[kb + 2], acc);
            acc = dot2(__builtin_bit_cast(h2, Wd.w), v2[kb + 3], acc);
        }
        scratch[jc * 256 + h] = acc;
    }
    __syncthreads();
    if (tid == 0) svv_sh = 0.5f * (red[0] + red[1] + red[2] + red[3]);
    if (tid < 256)
        dvLds[tid] = make_float2(pnLds[tid] + scratch[tid] + scratch[256 + tid] +
                                 scratch[512 + tid] + scratch[768 + tid], vvreg);
    __syncthreads();
    const float SVv = svv_sh;

    const u16* uqT_b = uqT + (size_t)b * 256 * 1024;
    const float* up_b = up + (size_t)b * Nn * 256;

    long long budget = 1LL << 26;
    float mloc, sumloc;

    for (int t = 0; t < Nn; ++t) {
        // ---- B: s-partials from LDS-resident Wuq; thread = (h-chunk, m-pair) ----
        {
            const int m2 = (tid & 127) * 2;
            const int hc = tid >> 7;                       // 0..7
            float a0 = 0.f, a1 = 0.f;
            const u16* wrow = &WuqL[(hc * 32) * 256 + m2];
#pragma unroll 8
            for (int hh = 0; hh < 32; ++hh) {
                float2 dv = dvLds[hc * 32 + hh];           // broadcast b64
                unsigned w2 = *(const unsigned*)wrow;
                wrow += 256;
                float w0 = us2f((u16)(w2 & 0xffffu));
                float w1 = us2f((u16)(w2 >> 16));
                a0 = fmaf(dv.y, rcp_fast(1.f + exp2_fast(w0 + dv.x)), a0);
                a1 = fmaf(dv.y, rcp_fast(1.f + exp2_fast(w1 + dv.x)), a1);
            }
            ((float2*)scratch)[hc * 128 + (tid & 127)] = make_float2(a0, a1);
        }
        __syncthreads();

        // ---- local softmax over this block's 256 m (redundant x4 wave-groups) ----
        {
            const int m = tid & 255;
            float sv = SVv;
#pragma unroll
            for (int c2 = 0; c2 < 8; ++c2) sv -= scratch[c2 * 256 + m];
            float mx = wmax(sv);
            if ((tid & 63) == 0) red[tid >> 6] = mx;
            __syncthreads();
            mloc = red[0];
#pragma unroll
            for (int w2 = 1; w2 < 16; ++w2) mloc = fmaxf(mloc, red[w2]);
            float ev = __expf(sv - mloc);
            if (tid < 256) eLds[m] = ev;
            float sm = wsum(ev);
            if ((tid & 63) == 0) red[16 + (tid >> 6)] = sm;
            __syncthreads();
            sumloc = red[16] + red[17] + red[18] + red[19];
        }

        // ---- D: cpart[i] = sum_m e[m]*uqT[i][m]; one 128B line per thread ----
        {
            const int i = tid & 255, mc = tid >> 8;        // mc 0..3
            const uint4* up4 = (const uint4*)(uqT_b + (size_t)i * 1024 + q * 256 + mc * 64);
            float acc = 0.f;
#pragma unroll
            for (int c4 = 0; c4 < 8; ++c4) {
                uint4 U = up4[c4];                         // 8 f16
                const float* ep = &eLds[mc * 64 + c4 * 8];
                h2 p0 = __builtin_bit_cast(h2, U.x);
                h2 p1 = __builtin_bit_cast(h2, U.y);
                h2 p2 = __builtin_bit_cast(h2, U.z);
                h2 p3 = __builtin_bit_cast(h2, U.w);
                acc = fmaf(ep[0], (float)p0.x, acc);
                acc = fmaf(ep[1], (float)p0.y, acc);
                acc = fmaf(ep[2], (float)p1.x, acc);
                acc = fmaf(ep[3], (float)p1.y, acc);
                acc = fmaf(ep[4], (float)p2.x, acc);
                acc = fmaf(ep[5], (float)p2.y, acc);
                acc = fmaf(ep[6], (float)p3.x, acc);
                acc = fmaf(ep[7], (float)p3.y, acc);
            }
            scratch[mc * 256 + i] = acc;
        }
        __syncthreads();
        if (tid < 256)
            cpartB[q * 256 + tid] = scratch[tid] + scratch[256 + tid] +
                                    scratch[512 + tid] + scratch[768 + tid];
        if (tid == 0) { mlsB[2 * q] = mloc; mlsB[2 * q + 1] = sumloc; }

        group_barrier(ctr + 0, 4u * (unsigned)(t + 1), budget);

        // ---- combine softmax across blocks; r = [up_t, c] ----
        if (tid < 256) {
            float m0 = mlsB[0], s0 = mlsB[1], m1 = mlsB[2], s1 = mlsB[3];
            float m2 = mlsB[4], s2 = mlsB[5], m3 = mlsB[6], s3 = mlsB[7];
            float Mg = fmaxf(fmaxf(m0, m1), fmaxf(m2, m3));
            float w0 = __expf(m0 - Mg), w1 = __expf(m1 - Mg);
            float w2 = __expf(m2 - Mg), w3 = __expf(m3 - Mg);
            float denom = s0 * w0 + s1 * w1 + s2 * w2 + s3 * w3;
            float c = cpartB[tid] * w0 + cpartB[256 + tid] * w1 +
                      cpartB[512 + tid] * w2 + cpartB[768 + tid] * w3;
            c *= rcp_fast(denom);
            float uval = up_b[(size_t)t * 256 + tid];
            rLds[tid] = uval;       rH[tid] = f2h(uval);
            rLds[256 + tid] = c;    rH[256 + tid] = f2h(c);
        }
        __syncthreads();

        // ---- E: g = sigmoid(Wg2 @ r) for this block's 64 outputs ----
        {
            const int o = tid & 63, ks = tid >> 6;         // 16 chunks of 32 k
            const uint4* wg = (const uint4*)(Wg216 + (size_t)(64 * q + o) * 512 + ks * 32);
            const h2* r2 = (const h2*)rH;
            float acc = 0.f;
#pragma unroll
            for (int c8 = 0; c8 < 4; ++c8) {
                uint4 Wd = wg[c8];
                int kb = ks * 16 + c8 * 4;
                acc = dot2(__builtin_bit_cast(h2, Wd.x), r2[kb + 0], acc);
                acc = dot2(__builtin_bit_cast(h2, Wd.y), r2[kb + 1], acc);
                acc = dot2(__builtin_bit_cast(h2, Wd.z), r2[kb + 2], acc);
                acc = dot2(__builtin_bit_cast(h2, Wd.w), r2[kb + 3], acc);
            }
            scratch[ks * 64 + o] = acc;
        }
        __syncthreads();
        if (tid < 64) {
            float acc = 0.f;
#pragma unroll
            for (int c2 = 0; c2 < 16; ++c2) acc += scratch[c2 * 64 + tid];
            float g = rcp_fast(1.f + __expf(-acc));
            cLdsH[tid] = f2h(g * rLds[256 + 64 * q + tid]);
        }
        __syncthreads();

        // ---- F: gi/gh partials over this block's 64-k slice ----
        if (tid < 768) {
            const uint4* wi = (const uint4*)(wih16 + (size_t)tid * 256 + q * 64);
            const uint4* wh = (const uint4*)(whh16 + (size_t)tid * 256 + q * 64);
            const h2* c2 = (const h2*)cLdsH;
            const h2* v2 = (const h2*)vHu;
            float gi = 0.f, gh = 0.f;
#pragma unroll
            for (int c8 = 0; c8 < 8; ++c8) {
                uint4 Wd = wi[c8];
                int kb = c8 * 4;
                gi = dot2(__builtin_bit_cast(h2, Wd.x), c2[kb + 0], gi);
                gi = dot2(__builtin_bit_cast(h2, Wd.y), c2[kb + 1], gi);
                gi = dot2(__builtin_bit_cast(h2, Wd.z), c2[kb + 2], gi);
                gi = dot2(__builtin_bit_cast(h2, Wd.w), c2[kb + 3], gi);
                uint4 Hd = wh[c8];
                int vb = 32 * q + kb;
                gh = dot2(__builtin_bit_cast(h2, Hd.x), v2[vb + 0], gh);
                gh = dot2(__builtin_bit_cast(h2, Hd.y), v2[vb + 1], gh);
                gh = dot2(__builtin_bit_cast(h2, Hd.z), v2[vb + 2], gh);
                gh = dot2(__builtin_bit_cast(h2, Hd.w), v2[vb + 3], gh);
            }
            giPB[q * 768 + tid] = gi;
            ghPB[q * 768 + tid] = gh;
        } else if (t + 1 < Nn) {
            const int h = tid - 768;
            pnLds[h] = us2f(Pm[((size_t)b * Nn + t + 1) * 256 + h]);
        }

        group_barrier(ctr + 1, 4u * (unsigned)(t + 1), budget);

        // ---- gates (redundant per block) + v update ----
        if (tid < 256) {
            const int h = tid;
            float gir = giPB[h] + giPB[768 + h] + giPB[1536 + h] + giPB[2304 + h] + bihs[h];
            float giz = giPB[256 + h] + giPB[1024 + h] + giPB[1792 + h] + giPB[2560 + h] + bihs[256 + h];
            float gin = giPB[512 + h] + giPB[1280 + h] + giPB[2048 + h] + giPB[2816 + h] + bihs[512 + h];
            float ghr = ghPB[h] + ghPB[768 + h] + ghPB[1536 + h] + ghPB[2304 + h] + bhhs[h];
            float ghz = ghPB[256 + h] + ghPB[1024 + h] + ghPB[1792 + h] + ghPB[2560 + h] + bhhs[256 + h];
            float ghn = ghPB[512 + h] + ghPB[1280 + h] + ghPB[2048 + h] + ghPB[2816 + h] + bhhs[512 + h];
            float rr = rcp_fast(1.f + __expf(-(gir + ghr)));
            float zz = rcp_fast(1.f + __expf(-(giz + ghz)));
            float narg = gin + rr * ghn;
            float nn = 1.f - 2.f * rcp_fast(1.f + __expf(2.f * narg));
            float vnew = (1.f - zz) * nn + zz * vLds[h];
            if ((h >> 6) == q) out[((size_t)t * Bn + b) * 256 + h] = vnew;
            vLds[h] = vnew;
            vHu[h] = f2h(vnew);
        }
        __syncthreads();
        // ---- d for t+1 ----
        if (t + 1 < Nn) {
            {
                const int h = tid & 255, jc = tid >> 8;
                const uint4* wr = (const uint4*)(Wv16 + (size_t)h * 256 + jc * 64);
                const h2* v2 = (const h2*)vHu;
                float acc = 0.f;
#pragma unroll
                for (int c8 = 0; c8 < 8; ++c8) {
                    uint4 Wd = wr[c8];
                    int kb = jc * 32 + c8 * 4;
                    acc = dot2(__builtin_bit_cast(h2, Wd.x), v2[kb + 0], acc);
                    acc = dot2(__builtin_bit_cast(h2, Wd.y), v2[kb + 1], acc);
                    acc = dot2(__builtin_bit_cast(h2, Wd.z), v2[kb + 2], acc);
                    acc = dot2(__builtin_bit_cast(h2, Wd.w), v2[kb + 3], acc);
                }
                scratch[jc * 256 + h] = acc;
            }
            __syncthreads();
            if (tid < 256)
                dvLds[tid] = make_float2(pnLds[tid] + scratch[tid] + scratch[256 + tid] +
                                         scratch[512 + tid] + scratch[768 + tid], vvreg);
            __syncthreads();
        }
    }
}

extern "C" void kernel_launch(void* const* d_in, const int* in_sizes, int n_in,
                              void* d_out, int out_size, void* d_ws, size_t ws_size,
                              hipStream_t stream) {
    const float* up   = (const float*)d_in[0];
    const float* uq   = (const float*)d_in[1];
    const float* v0   = (const float*)d_in[2];
    const float* V    = (const float*)d_in[3];
    const float* Wp   = (const float*)d_in[4];
    const float* Wq   = (const float*)d_in[5];
    const float* Wv   = (const float*)d_in[6];
    const float* Wg   = (const float*)d_in[7];
    const float* w_ih = (const float*)d_in[8];
    const float* w_hh = (const float*)d_in[9];
    const float* b_ih = (const float*)d_in[10];
    const float* b_hh = (const float*)d_in[11];
    float* out = (float*)d_out;

    char* ws = (char*)d_ws;
    unsigned int* ctrs = (unsigned int*)ws;                  // 4 KB
    float* gdata = (float*)(ws + 4096);                      // 64*7680 f32
    u16* WuqT = (u16*)(ws + (size_t)(2u << 20));             // [64][256 h][1024 m] f16, 32 MB
    u16* Pm   = WuqT + (size_t)Bn * 256 * 1024;              // [64][1024 t][256 h] f16, 32 MB
    u16* uqT  = Pm + (size_t)Bn * Nn * 256;                  // [64][256 i][1024 m] f16, 32 MB
    u16* Wv16 = uqT + (size_t)Bn * 256 * 1024;               // [256 h][256 j] f16 (K-scaled)
    u16* wih16 = Wv16 + 65536;                               // [768 j][256 k] f16
    u16* whh16 = wih16 + 196608;                             // [768 j][256 k] f16
    u16* Wg216 = whh16 + 196608;                             // [256 o][512 k] f16

    hipMemsetAsync(ctrs, 0, 4096, stream);

    hipLaunchKernelGGL(gemm_f16, dim3(2048), dim3(256), 0, stream,
                       uq, Wq, (u16*)nullptr, WuqT, 1, KSCALE);
    hipLaunchKernelGGL(gemm_f16, dim3(2048), dim3(256), 0, stream,
                       up, Wp, Pm, (u16*)nullptr, 0, KSCALE);
    hipLaunchKernelGGL(uq_f16T, dim3(16384), dim3(256), 0, stream, uq, uqT);
    hipLaunchKernelGGL(cast_f16s, dim3(256), dim3(256), 0, stream, Wv, Wv16, 65536, KSCALE);
    hipLaunchKernelGGL(cast_f16s, dim3(768), dim3(256), 0, stream, w_ih, wih16, 196608, 1.0f);
    hipLaunchKernelGGL(cast_f16s, dim3(768), dim3(256), 0, stream, w_hh, whh16, 196608, 1.0f);
    hipLaunchKernelGGL(cast_f16s, dim3(512), dim3(256), 0, stream, Wg + 512 * 256, Wg216, 131072, 1.0f);

    hipLaunchKernelGGL(scan_kernel, dim3(256), dim3(1024), 0, stream,
                       up, v0, V, b_ih, b_hh,
                       WuqT, Pm, uqT, Wv16, wih16, whh16, Wg216,
                       out, ctrs, gdata);
}

// Round 5
// 29509.921 us; speedup vs baseline: 3.2310x; 3.2310x over previous
//
#include <hip/hip_runtime.h>

#define Bn 64
#define Nn 1024
#define Mn 1024
#define GSTR 7680
// scale = 2*log2(e): exp2(scale*x) = exp(2x)
#define KSCALE 2.8853900817779268f

typedef unsigned short u16;
typedef _Float16 h2 __attribute__((ext_vector_type(2)));

__device__ __forceinline__ float us2f(u16 u) {
    _Float16 h = __builtin_bit_cast(_Float16, u);
    return (float)h;
}
__device__ __forceinline__ u16 f2h(float f) {
    _Float16 h = (_Float16)f;
    return __builtin_bit_cast(u16, h);
}
__device__ __forceinline__ float rcp_fast(float x) {
#if __has_builtin(__builtin_amdgcn_rcpf)
    return __builtin_amdgcn_rcpf(x);
#else
    return 1.0f / x;
#endif
}
__device__ __forceinline__ float exp2_fast(float x) {
#if __has_builtin(__builtin_amdgcn_exp2f)
    return __builtin_amdgcn_exp2f(x);
#else
    return exp2f(x);
#endif
}
__device__ __forceinline__ float wsum(float x) {
#pragma unroll
    for (int m = 32; m > 0; m >>= 1) x += __shfl_xor(x, m, 64);
    return x;
}
__device__ __forceinline__ float wmax(float x) {
#pragma unroll
    for (int m = 32; m > 0; m >>= 1) x = fmaxf(x, __shfl_xor(x, m, 64));
    return x;
}
__device__ __forceinline__ float dot2(unsigned a, unsigned b, float c) {
#if __has_builtin(__builtin_amdgcn_fdot2)
    return __builtin_amdgcn_fdot2(__builtin_bit_cast(h2, a), __builtin_bit_cast(h2, b), c, false);
#else
    h2 av = __builtin_bit_cast(h2, a), bv = __builtin_bit_cast(h2, b);
    return c + (float)av.x * (float)bv.x + (float)av.y * (float)bv.y;
#endif
}
// system-scope (LLC-coherent) relaxed accesses: no cache-maintenance instructions
__device__ __forceinline__ void sysst(float* p, float v) {
    __hip_atomic_store(p, v, __ATOMIC_RELAXED, __HIP_MEMORY_SCOPE_SYSTEM);
}
__device__ __forceinline__ float sysld(float* p) {
    return __hip_atomic_load(p, __ATOMIC_RELAXED, __HIP_MEMORY_SCOPE_SYSTEM);
}

// ---------- precompute: 32-row tile of  out = scale * U @ W^T  (f16 out) ----------
__global__ __launch_bounds__(256)
void gemm_f16(const float* __restrict__ U, const float* __restrict__ W,
              u16* __restrict__ outN, u16* __restrict__ outT,
              int transposed, float scale) {
    __shared__ float WL[256 * 33];
    __shared__ float uL[32 * 33];
    const int tid = threadIdx.x;
    const size_t row0 = (size_t)blockIdx.x * 32;
    float acc[32];
#pragma unroll
    for (int m = 0; m < 32; ++m) acc[m] = 0.f;
    for (int ic = 0; ic < 8; ++ic) {
        __syncthreads();
        for (int e = tid; e < 8192; e += 256) {
            int h = e >> 5, ii = e & 31;
            WL[h * 33 + ii] = W[h * 256 + ic * 32 + ii];
        }
        for (int e = tid; e < 1024; e += 256) {
            int r = e >> 5, ii = e & 31;
            uL[r * 33 + ii] = U[(row0 + r) * 256 + ic * 32 + ii];
        }
        __syncthreads();
#pragma unroll 4
        for (int ii = 0; ii < 32; ++ii) {
            float w = WL[tid * 33 + ii];
#pragma unroll
            for (int m = 0; m < 32; ++m)
                acc[m] = fmaf(w, uL[m * 33 + ii], acc[m]);
        }
    }
    if (!transposed) {
#pragma unroll
        for (int m = 0; m < 32; ++m)
            outN[(row0 + m) * 256 + tid] = f2h(scale * acc[m]);
    } else {
        __syncthreads();
#pragma unroll
        for (int m = 0; m < 32; ++m) WL[tid * 33 + m] = acc[m];
        __syncthreads();
        const size_t batch = row0 >> 10;
        const int m0 = (int)(row0 & 1023);
        for (int e = tid; e < 8192; e += 256) {
            int h = e >> 5, mm = e & 31;
            outT[(batch * 256 + h) * 1024 + m0 + mm] = f2h(scale * WL[h * 33 + mm]);
        }
    }
}

// generic pack: src f32 [R][C]  ->  dst f16 [C/8][R][8]  (k-pairs along reduction dim)
__global__ void pack8(const float* __restrict__ src, u16* __restrict__ dst,
                      int R, int C, float scale) {
    int idx = blockIdx.x * blockDim.x + threadIdx.x;
    int total = R * (C >> 3);
    if (idx >= total) return;
    int c8 = idx / R, r = idx - c8 * R;
    u16 pk[8];
#pragma unroll
    for (int e = 0; e < 8; ++e) pk[e] = f2h(scale * src[(size_t)r * C + c8 * 8 + e]);
    *(uint4*)&dst[(size_t)idx * 8] = *(uint4*)pk;
}

// uq f32 [64][1024 m][256 i] -> uqP f16 [64][m8=128][i=256][8]
__global__ __launch_bounds__(256)
void uq_pack(const float* __restrict__ uq, u16* __restrict__ out) {
    __shared__ float T[32][65];
    const int blk = blockIdx.x;
    const int ib = blk & 3, mt = (blk >> 2) & 31, b = blk >> 7;
    const int tid = threadIdx.x;
#pragma unroll
    for (int s = 0; s < 8; ++s) {
        int idx = tid + 256 * s, mm = idx >> 6, ii = idx & 63;
        T[mm][ii] = uq[((size_t)b * 1024 + mt * 32 + mm) * 256 + ib * 64 + ii];
    }
    __syncthreads();
    const int mo = tid >> 6, ii = tid & 63;
    u16 pk[8];
#pragma unroll
    for (int e = 0; e < 8; ++e) pk[e] = f2h(T[mo * 8 + e][ii]);
    *(uint4*)&out[(((size_t)b * 128 + mt * 4 + mo) * 256 + ib * 64 + ii) * 8] = *(uint4*)pk;
}

// -------- 4-block group barrier: system-scope relaxed counter --------
__device__ __forceinline__ void sysbar(unsigned int* ctr, unsigned int target,
                                       long long& budget) {
    __syncthreads();   // compiler drains vmcnt before s_barrier -> all block stores done
    if (threadIdx.x == 0) {
        asm volatile("s_waitcnt vmcnt(0)" ::: "memory");
        __hip_atomic_fetch_add(ctr, 1u, __ATOMIC_RELAXED, __HIP_MEMORY_SCOPE_SYSTEM);
        while (__hip_atomic_load(ctr, __ATOMIC_RELAXED, __HIP_MEMORY_SCOPE_SYSTEM) < target) {
            __builtin_amdgcn_s_sleep(1);
            if (--budget < 0) break;   // fail fast instead of deadlocking
        }
    }
    __syncthreads();
}

__global__ __launch_bounds__(1024, 4)
void scan_kernel(const float* __restrict__ up, const float* __restrict__ v0,
                 const float* __restrict__ V, const float* __restrict__ b_ih,
                 const float* __restrict__ b_hh,
                 const u16* __restrict__ WuqT, const u16* __restrict__ Pm,
                 const u16* __restrict__ uqP, const u16* __restrict__ WvP,
                 const u16* __restrict__ wihP, const u16* __restrict__ whhP,
                 const u16* __restrict__ Wg2P,
                 float* __restrict__ out, unsigned int* __restrict__ ctrs,
                 float* __restrict__ gdata) {
    const int tid = threadIdx.x;
    const int bid = blockIdx.x;
    // co-locate a batch's 4 blocks on one XCD (bid%8 = XCD under round-robin dispatch)
    const int x = bid & 7, q = (bid >> 3) & 3, bhi = bid >> 5;
    const int b = (bhi << 3) | x;

    unsigned int* ctr = ctrs + b * 16;
    float* gb = gdata + (size_t)b * GSTR;
    float* cpartB = gb;          // [4][256]
    float* mlsB   = gb + 1024;   // [8]
    float* giPB   = gb + 1032;   // [4][768]
    float* ghPB   = gb + 4104;   // [4][768]

    __shared__ __align__(16) u16 WuqL[256 * 256];    // [h][m-slice] f16, 128 KB
    __shared__ __align__(16) float scratch[8 * 256];
    __shared__ __align__(16) float2 dvLds[256];      // .x = d (K-scaled), .y = 2*V
    __shared__ __align__(16) float vLds[256], pnLds[256];
    __shared__ __align__(16) u16 eH[256], rH[512], vHu[256], cH[64];
    __shared__ __align__(16) float bihs[768], bhhs[768];
    __shared__ float red[32];
    __shared__ float svv_sh;

    // ---- one-time: stage this block's Wuq m-slice into LDS ----
    {
        const u16* src = WuqT + (size_t)b * 256 * 1024 + q * 256;
        for (int d = tid; d < 32768; d += 1024) {          // dwords
            int h = d >> 7, mp = d & 127;
            ((unsigned*)WuqL)[d] = *(const unsigned*)(src + (size_t)h * 1024 + mp * 2);
        }
    }
    if (tid < 768) { bihs[tid] = b_ih[tid]; bhhs[tid] = b_hh[tid]; }
    float vvreg = 0.f;
    if (tid < 256) {
        float v = v0[b * 256 + tid];
        vLds[tid] = v;
        vHu[tid] = f2h(v);
        vvreg = 2.0f * V[b * 256 + tid];
        pnLds[tid] = us2f(Pm[(size_t)b * Nn * 256 + tid]);
    }
    __syncthreads();
    if (tid < 256) {
        float s = wsum(vvreg);
        if ((tid & 63) == 0) red[tid >> 6] = s;
    }
    // initial d = pn + Wv@v0 (K-scaled): coalesced packed loads
    {
        const int h = tid & 255, jc = tid >> 8;
        const uint4* wv = (const uint4*)WvP;
        const unsigned* vH32 = (const unsigned*)vHu;
        float acc = 0.f;
#pragma unroll
        for (int l = 0; l < 8; ++l) {
            uint4 Wd = wv[(size_t)(jc * 8 + l) * 256 + h];
            int vb = jc * 32 + l * 4;
            acc = dot2(Wd.x, vH32[vb + 0], acc);
            acc = dot2(Wd.y, vH32[vb + 1], acc);
            acc = dot2(Wd.z, vH32[vb + 2], acc);
            acc = dot2(Wd.w, vH32[vb + 3], acc);
        }
        scratch[jc * 256 + h] = acc;
    }
    __syncthreads();
    if (tid == 0) svv_sh = 0.5f * (red[0] + red[1] + red[2] + red[3]);
    if (tid < 256)
        dvLds[tid] = make_float2(pnLds[tid] + scratch[tid] + scratch[256 + tid] +
                                 scratch[512 + tid] + scratch[768 + tid], vvreg);
    __syncthreads();
    const float SVv = svv_sh;

    const uint4* uqP_b = (const uint4*)(uqP + (size_t)b * 128 * 256 * 8);
    const float* up_b = up + (size_t)b * Nn * 256;

    long long budget = 1LL << 26;
    float mloc, sumloc;

    for (int t = 0; t < Nn; ++t) {
        // ---- B: s-partials from LDS-resident Wuq; thread = (h-chunk, m-pair) ----
        {
            const int m2 = (tid & 127) * 2;
            const int hc = tid >> 7;                       // 0..7, wave-uniform
            float a0 = 0.f, a1 = 0.f;
            const u16* wrow = &WuqL[(hc * 32) * 256 + m2];
#pragma unroll 8
            for (int hh = 0; hh < 32; ++hh) {
                float2 dv = dvLds[hc * 32 + hh];           // broadcast
                unsigned w2 = *(const unsigned*)wrow;
                wrow += 256;
                float w0 = us2f((u16)(w2 & 0xffffu));
                float w1 = us2f((u16)(w2 >> 16));
                a0 = fmaf(dv.y, rcp_fast(1.f + exp2_fast(w0 + dv.x)), a0);
                a1 = fmaf(dv.y, rcp_fast(1.f + exp2_fast(w1 + dv.x)), a1);
            }
            ((float2*)scratch)[hc * 128 + (tid & 127)] = make_float2(a0, a1);
        }
        __syncthreads();

        // ---- local softmax over this block's 256 m (x4 redundant wave-groups) ----
        {
            const int m = tid & 255;
            float sv = SVv;
#pragma unroll
            for (int c2 = 0; c2 < 8; ++c2) sv -= scratch[c2 * 256 + m];
            float mx = wmax(sv);
            if ((tid & 63) == 0) red[tid >> 6] = mx;
            __syncthreads();
            mloc = red[0];
#pragma unroll
            for (int w2 = 1; w2 < 16; ++w2) mloc = fmaxf(mloc, red[w2]);
            float ev = __expf(sv - mloc);
            if (tid < 256) eH[m] = f2h(ev);
            float sm = wsum(ev);
            if ((tid & 63) == 0) red[16 + (tid >> 6)] = sm;
            __syncthreads();
            sumloc = red[16] + red[17] + red[18] + red[19];
        }

        // ---- D: cpart[i] = sum_m e[m]*uq[m][i]; packed coalesced (16B/lane) ----
        {
            const int i = tid & 255, mc = tid >> 8;        // mc 0..3 wave-uniform
            const unsigned* eH32 = (const unsigned*)eH;
            float acc = 0.f;
#pragma unroll
            for (int l = 0; l < 8; ++l) {
                uint4 U = uqP_b[(size_t)(q * 32 + mc * 8 + l) * 256 + i];
                int eb = mc * 32 + l * 4;
                acc = dot2(U.x, eH32[eb + 0], acc);
                acc = dot2(U.y, eH32[eb + 1], acc);
                acc = dot2(U.z, eH32[eb + 2], acc);
                acc = dot2(U.w, eH32[eb + 3], acc);
            }
            scratch[mc * 256 + i] = acc;
        }
        __syncthreads();
        if (tid < 256)
            sysst(&cpartB[q * 256 + tid], scratch[tid] + scratch[256 + tid] +
                                          scratch[512 + tid] + scratch[768 + tid]);
        if (tid == 0) { sysst(&mlsB[2 * q], mloc); sysst(&mlsB[2 * q + 1], sumloc); }

        sysbar(ctr + 0, 4u * (unsigned)(t + 1), budget);

        // ---- combine softmax across blocks; r = [up_t, c] ----
        {
            float cp0 = 0.f, cp1 = 0.f, cp2 = 0.f, cp3 = 0.f, upv = 0.f;
            if (tid < 256) {
                cp0 = sysld(&cpartB[tid]);       cp1 = sysld(&cpartB[256 + tid]);
                cp2 = sysld(&cpartB[512 + tid]); cp3 = sysld(&cpartB[768 + tid]);
                upv = up_b[(size_t)t * 256 + tid];
            }
            if (tid < 8) red[tid] = sysld(&mlsB[tid]);
            __syncthreads();
            if (tid < 256) {
                float m0 = red[0], s0 = red[1], m1 = red[2], s1 = red[3];
                float m2 = red[4], s2 = red[5], m3 = red[6], s3 = red[7];
                float Mg = fmaxf(fmaxf(m0, m1), fmaxf(m2, m3));
                float w0 = __expf(m0 - Mg), w1 = __expf(m1 - Mg);
                float w2 = __expf(m2 - Mg), w3 = __expf(m3 - Mg);
                float denom = s0 * w0 + s1 * w1 + s2 * w2 + s3 * w3;
                float c = cp0 * w0 + cp1 * w1 + cp2 * w2 + cp3 * w3;
                c *= rcp_fast(denom);
                rH[tid] = f2h(upv);
                rH[256 + tid] = f2h(c);
            }
            __syncthreads();
        }

        // ---- E: g = sigmoid(Wg2 @ r) for this block's 64 outputs ----
        {
            const int o = tid & 63, ks = tid >> 6;         // ks 0..15 wave-uniform
            const uint4* wg = (const uint4*)Wg2P;
            const unsigned* rH32 = (const unsigned*)rH;
            float acc = 0.f;
#pragma unroll
            for (int l = 0; l < 4; ++l) {
                int k8 = ks * 4 + l;
                uint4 Wd = wg[(size_t)k8 * 256 + q * 64 + o];
                int kb = k8 * 4;
                acc = dot2(Wd.x, rH32[kb + 0], acc);
                acc = dot2(Wd.y, rH32[kb + 1], acc);
                acc = dot2(Wd.z, rH32[kb + 2], acc);
                acc = dot2(Wd.w, rH32[kb + 3], acc);
            }
            scratch[ks * 64 + o] = acc;
        }
        __syncthreads();
        if (tid < 64) {
            float acc = 0.f;
#pragma unroll
            for (int c2 = 0; c2 < 16; ++c2) acc += scratch[c2 * 64 + tid];
            float g = rcp_fast(1.f + __expf(-acc));
            cH[tid] = f2h(g * us2f(rH[256 + 64 * q + tid]));
        }
        __syncthreads();

        // ---- F: gi/gh partials over this block's 64-k slice (coalesced packed) ----
        if (tid < 768) {
            const uint4* wi = (const uint4*)wihP;
            const uint4* wh = (const uint4*)whhP;
            const unsigned* cH32 = (const unsigned*)cH;
            const unsigned* vH32 = (const unsigned*)vHu;
            float gi = 0.f, gh = 0.f;
#pragma unroll
            for (int l = 0; l < 8; ++l) {
                uint4 Wd = wi[(size_t)(q * 8 + l) * 768 + tid];
                int kb = l * 4;
                gi = dot2(Wd.x, cH32[kb + 0], gi);
                gi = dot2(Wd.y, cH32[kb + 1], gi);
                gi = dot2(Wd.z, cH32[kb + 2], gi);
                gi = dot2(Wd.w, cH32[kb + 3], gi);
                uint4 Hd = wh[(size_t)(q * 8 + l) * 768 + tid];
                int vb = q * 32 + l * 4;
                gh = dot2(Hd.x, vH32[vb + 0], gh);
                gh = dot2(Hd.y, vH32[vb + 1], gh);
                gh = dot2(Hd.z, vH32[vb + 2], gh);
                gh = dot2(Hd.w, vH32[vb + 3], gh);
            }
            sysst(&giPB[q * 768 + tid], gi);
            sysst(&ghPB[q * 768 + tid], gh);
        } else if (t + 1 < Nn) {
            const int h = tid - 768;
            pnLds[h] = us2f(Pm[((size_t)b * Nn + t + 1) * 256 + h]);
        }

        sysbar(ctr + 1, 4u * (unsigned)(t + 1), budget);

        // ---- gates (redundant per block) + v update ----
        if (tid < 256) {
            const int h = tid;
            float gir = sysld(&giPB[h]) + sysld(&giPB[768 + h]) +
                        sysld(&giPB[1536 + h]) + sysld(&giPB[2304 + h]) + bihs[h];
            float giz = sysld(&giPB[256 + h]) + sysld(&giPB[1024 + h]) +
                        sysld(&giPB[1792 + h]) + sysld(&giPB[2560 + h]) + bihs[256 + h];
            float gin = sysld(&giPB[512 + h]) + sysld(&giPB[1280 + h]) +
                        sysld(&giPB[2048 + h]) + sysld(&giPB[2816 + h]) + bihs[512 + h];
            float ghr = sysld(&ghPB[h]) + sysld(&ghPB[768 + h]) +
                        sysld(&ghPB[1536 + h]) + sysld(&ghPB[2304 + h]) + bhhs[h];
            float ghz = sysld(&ghPB[256 + h]) + sysld(&ghPB[1024 + h]) +
                        sysld(&ghPB[1792 + h]) + sysld(&ghPB[2560 + h]) + bhhs[256 + h];
            float ghn = sysld(&ghPB[512 + h]) + sysld(&ghPB[1280 + h]) +
                        sysld(&ghPB[2048 + h]) + sysld(&ghPB[2816 + h]) + bhhs[512 + h];
            float rr = rcp_fast(1.f + __expf(-(gir + ghr)));
            float zz = rcp_fast(1.f + __expf(-(giz + ghz)));
            float narg = gin + rr * ghn;
            float nn = 1.f - 2.f * rcp_fast(1.f + __expf(2.f * narg));
            float vnew = (1.f - zz) * nn + zz * vLds[h];
            if ((h >> 6) == q) out[((size_t)t * Bn + b) * 256 + h] = vnew;
            vLds[h] = vnew;
            vHu[h] = f2h(vnew);
        }
        __syncthreads();
        // ---- d for t+1 (coalesced packed Wv) ----
        if (t + 1 < Nn) {
            {
                const int h = tid & 255, jc = tid >> 8;
                const uint4* wv = (const uint4*)WvP;
                const unsigned* vH32 = (const unsigned*)vHu;
                float acc = 0.f;
#pragma unroll
                for (int l = 0; l < 8; ++l) {
                    uint4 Wd = wv[(size_t)(jc * 8 + l) * 256 + h];
                    int vb = jc * 32 + l * 4;
                    acc = dot2(Wd.x, vH32[vb + 0], acc);
                    acc = dot2(Wd.y, vH32[vb + 1], acc);
                    acc = dot2(Wd.z, vH32[vb + 2], acc);
                    acc = dot2(Wd.w, vH32[vb + 3], acc);
                }
                scratch[jc * 256 + h] = acc;
            }
            __syncthreads();
            if (tid < 256)
                dvLds[tid] = make_float2(pnLds[tid] + scratch[tid] + scratch[256 + tid] +
                                         scratch[512 + tid] + scratch[768 + tid], vvreg);
            __syncthreads();
        }
    }
}

extern "C" void kernel_launch(void* const* d_in, const int* in_sizes, int n_in,
                              void* d_out, int out_size, void* d_ws, size_t ws_size,
                              hipStream_t stream) {
    const float* up   = (const float*)d_in[0];
    const float* uq   = (const float*)d_in[1];
    const float* v0   = (const float*)d_in[2];
    const float* V    = (const float*)d_in[3];
    const float* Wp   = (const float*)d_in[4];
    const float* Wq   = (const float*)d_in[5];
    const float* Wv   = (const float*)d_in[6];
    const float* Wg   = (const float*)d_in[7];
    const float* w_ih = (const float*)d_in[8];
    const float* w_hh = (const float*)d_in[9];
    const float* b_ih = (const float*)d_in[10];
    const float* b_hh = (const float*)d_in[11];
    float* out = (float*)d_out;

    char* ws = (char*)d_ws;
    unsigned int* ctrs = (unsigned int*)ws;                  // 4 KB
    float* gdata = (float*)(ws + 4096);                      // 64*7680 f32
    u16* WuqT = (u16*)(ws + (size_t)(2u << 20));             // [64][256 h][1024 m] f16, 32 MB
    u16* Pm   = WuqT + (size_t)Bn * 256 * 1024;              // [64][1024 t][256 h] f16, 32 MB
    u16* uqP  = Pm + (size_t)Bn * Nn * 256;                  // [64][128 m8][256 i][8] f16, 32 MB
    u16* WvP  = uqP + (size_t)Bn * 128 * 256 * 8;            // [32 j8][256 h][8] f16 (K-scaled)
    u16* wihP = WvP + 65536;                                 // [32 k8][768 j][8] f16
    u16* whhP = wihP + 196608;                               // [32 k8][768 j][8] f16
    u16* Wg2P = whhP + 196608;                               // [64 k8][256 o][8] f16

    hipMemsetAsync(ctrs, 0, 4096, stream);

    hipLaunchKernelGGL(gemm_f16, dim3(2048), dim3(256), 0, stream,
                       uq, Wq, (u16*)nullptr, WuqT, 1, KSCALE);
    hipLaunchKernelGGL(gemm_f16, dim3(2048), dim3(256), 0, stream,
                       up, Wp, Pm, (u16*)nullptr, 0, KSCALE);
    hipLaunchKernelGGL(uq_pack, dim3(8192), dim3(256), 0, stream, uq, uqP);
    hipLaunchKernelGGL(pack8, dim3(32), dim3(256), 0, stream, Wv, WvP, 256, 256, KSCALE);
    hipLaunchKernelGGL(pack8, dim3(96), dim3(256), 0, stream, w_ih, wihP, 768, 256, 1.0f);
    hipLaunchKernelGGL(pack8, dim3(96), dim3(256), 0, stream, w_hh, whhP, 768, 256, 1.0f);
    hipLaunchKernelGGL(pack8, dim3(64), dim3(256), 0, stream, Wg + 512 * 256, Wg2P, 256, 512, 1.0f);

    hipLaunchKernelGGL(scan_kernel, dim3(256), dim3(1024), 0, stream,
                       up, v0, V, b_ih, b_hh,
                       WuqT, Pm, uqP, WvP, wihP, whhP, Wg2P,
                       out, ctrs, gdata);
}